// Round 3
// baseline (1425.974 us; speedup 1.0000x reference)
//
#include <hip/hip_runtime.h>
#include <hip/hip_bf16.h>
#include <float.h>
#include <math.h>

#define L_SEQ 2048
#define NH 16
#define HD 64
// DIM = DIM_ATTN = 1024

// ---------------------------------------------------------------------------
// GEMM: C[4096,1024] = A[4096,1024] @ W[1024,1024]   (fp32, 128x128 tile,
// 256 threads, 8x8 per thread). blockIdx.z selects among up to 3 (W, C) pairs
// so QKV runs as one launch.
// ---------------------------------------------------------------------------
__global__ __launch_bounds__(256, 2) void gemm_f32(
    const float* __restrict__ A,
    const float* __restrict__ W0, const float* __restrict__ W1, const float* __restrict__ W2,
    float* __restrict__ C0, float* __restrict__ C1, float* __restrict__ C2)
{
    const float* W = (blockIdx.z == 0) ? W0 : (blockIdx.z == 1) ? W1 : W2;
    float*       C = (blockIdx.z == 0) ? C0 : (blockIdx.z == 1) ? C1 : C2;

    __shared__ float As[16][132];   // [k][m] transposed, padded stride 132
    __shared__ float Bs[16][132];   // [k][n] natural

    const int t  = threadIdx.x;
    const int tx = t & 15, ty = t >> 4;
    const int bm = blockIdx.x * 128, bn = blockIdx.y * 128;

    const int am  = t >> 2;          // 0..63 (rows am, am+64)
    const int ac  = (t & 3) << 2;    // 0,4,8,12
    const int bk  = t >> 5;          // 0..7 (rows bk, bk+8)
    const int bn4 = (t & 31) << 2;   // 0..124

    float acc[8][8];
#pragma unroll
    for (int i = 0; i < 8; ++i)
#pragma unroll
        for (int j = 0; j < 8; ++j) acc[i][j] = 0.f;

    for (int k0 = 0; k0 < 1024; k0 += 16) {
        float4 a0 = *(const float4*)&A[(size_t)(bm + am) * 1024 + k0 + ac];
        float4 a1 = *(const float4*)&A[(size_t)(bm + am + 64) * 1024 + k0 + ac];
        float4 b0 = *(const float4*)&W[(size_t)(k0 + bk) * 1024 + bn + bn4];
        float4 b1 = *(const float4*)&W[(size_t)(k0 + bk + 8) * 1024 + bn + bn4];
        __syncthreads();   // previous iteration's compute done
        As[ac + 0][am] = a0.x; As[ac + 1][am] = a0.y;
        As[ac + 2][am] = a0.z; As[ac + 3][am] = a0.w;
        As[ac + 0][am + 64] = a1.x; As[ac + 1][am + 64] = a1.y;
        As[ac + 2][am + 64] = a1.z; As[ac + 3][am + 64] = a1.w;
        *(float4*)&Bs[bk][bn4]     = b0;
        *(float4*)&Bs[bk + 8][bn4] = b1;
        __syncthreads();
#pragma unroll
        for (int kk = 0; kk < 16; ++kk) {
            float4 a_0 = *(const float4*)&As[kk][ty * 8];
            float4 a_1 = *(const float4*)&As[kk][ty * 8 + 4];
            float4 b_0 = *(const float4*)&Bs[kk][tx * 8];
            float4 b_1 = *(const float4*)&Bs[kk][tx * 8 + 4];
            float av[8] = {a_0.x, a_0.y, a_0.z, a_0.w, a_1.x, a_1.y, a_1.z, a_1.w};
            float bv[8] = {b_0.x, b_0.y, b_0.z, b_0.w, b_1.x, b_1.y, b_1.z, b_1.w};
#pragma unroll
            for (int i = 0; i < 8; ++i)
#pragma unroll
                for (int j = 0; j < 8; ++j)
                    acc[i][j] = fmaf(av[i], bv[j], acc[i][j]);
        }
    }
#pragma unroll
    for (int i = 0; i < 8; ++i) {
        size_t row = (size_t)(bm + ty * 8 + i) * 1024 + bn;
        *(float4*)&C[row + tx * 8]     = make_float4(acc[i][0], acc[i][1], acc[i][2], acc[i][3]);
        *(float4*)&C[row + tx * 8 + 4] = make_float4(acc[i][4], acc[i][5], acc[i][6], acc[i][7]);
    }
}

// ---------------------------------------------------------------------------
// Flash-style attention, fp32. One block = (head h, 64-row q-tile), both
// batches. 256 threads as (ty,tx)=16x16; each thread owns a 4x4 S/O subtile.
// Online softmax state lives in registers (replicated across the 16 tx lanes
// of each row-group via butterfly shuffles).
// ---------------------------------------------------------------------------
__global__ __launch_bounds__(256, 1) void attn_f32(
    const float* __restrict__ Qg, const float* __restrict__ Kg, const float* __restrict__ Vg,
    const float* __restrict__ bias, const int* __restrict__ mask,
    float* __restrict__ Aout)
{
    __shared__ float Qt[2][64][68];  // [b][dk][qi]
    __shared__ float Kt[2][64][68];  // [b][dk][kj]
    __shared__ float Vs[2][64][68];  // [b][kj][dk]
    __shared__ float Ps[2][64][68];  // [b][kj][qi]

    const int t  = threadIdx.x;
    const int tx = t & 15, ty = t >> 4;
    const int h  = blockIdx.y;
    const int q0 = blockIdx.x * 64;

    const int r  = t >> 4;          // 0..15 staging row
    const int c4 = (t & 15) << 2;   // 0..60 staging col (float4)

    // Stage Q transposed (once per block)
#pragma unroll
    for (int b = 0; b < 2; ++b)
#pragma unroll
        for (int i = 0; i < 4; ++i) {
            int qi = r + 16 * i;
            float4 v = *(const float4*)&Qg[((size_t)(b * L_SEQ + q0 + qi)) * 1024 + h * 64 + c4];
            Qt[b][c4 + 0][qi] = v.x; Qt[b][c4 + 1][qi] = v.y;
            Qt[b][c4 + 2][qi] = v.z; Qt[b][c4 + 3][qi] = v.w;
        }

    float O[2][4][4];
    float m_r[2][4], l_r[2][4], sc_r[2][4];
#pragma unroll
    for (int b = 0; b < 2; ++b)
#pragma unroll
        for (int i = 0; i < 4; ++i) {
            m_r[b][i] = -INFINITY; l_r[b][i] = 0.f; sc_r[b][i] = 0.f;
#pragma unroll
            for (int j = 0; j < 4; ++j) O[b][i][j] = 0.f;
        }

    for (int k0 = 0; k0 < L_SEQ; k0 += 64) {
        __syncthreads();   // previous PV done; LDS reusable (also covers Qt staging)
        // Stage K transposed + V natural for both batches
#pragma unroll
        for (int b = 0; b < 2; ++b)
#pragma unroll
            for (int i = 0; i < 4; ++i) {
                int kj = r + 16 * i;
                size_t g = ((size_t)(b * L_SEQ + k0 + kj)) * 1024 + h * 64 + c4;
                float4 kv = *(const float4*)&Kg[g];
                float4 vv = *(const float4*)&Vg[g];
                Kt[b][c4 + 0][kj] = kv.x; Kt[b][c4 + 1][kj] = kv.y;
                Kt[b][c4 + 2][kj] = kv.z; Kt[b][c4 + 3][kj] = kv.w;
                *(float4*)&Vs[b][kj][c4] = vv;
            }
        __syncthreads();

        // Bias tile (shared across batches) -> registers, no LDS staging
        float bv[4][4];
#pragma unroll
        for (int i = 0; i < 4; ++i) {
            float4 bb = *(const float4*)&bias[((size_t)h * L_SEQ + q0 + ty * 4 + i) * L_SEQ + k0 + tx * 4];
            bv[i][0] = bb.x; bv[i][1] = bb.y; bv[i][2] = bb.z; bv[i][3] = bb.w;
        }

#pragma unroll
        for (int b = 0; b < 2; ++b) {
            float s[4][4];
#pragma unroll
            for (int i = 0; i < 4; ++i)
#pragma unroll
                for (int j = 0; j < 4; ++j) s[i][j] = 0.f;

#pragma unroll 8
            for (int kk = 0; kk < 64; ++kk) {
                float4 q4 = *(const float4*)&Qt[b][kk][ty * 4];
                float4 k4 = *(const float4*)&Kt[b][kk][tx * 4];
                float qa[4] = {q4.x, q4.y, q4.z, q4.w};
                float ka[4] = {k4.x, k4.y, k4.z, k4.w};
#pragma unroll
                for (int i = 0; i < 4; ++i)
#pragma unroll
                    for (int j = 0; j < 4; ++j)
                        s[i][j] = fmaf(qa[i], ka[j], s[i][j]);
            }

            const int4 mk = *(const int4*)&mask[b * L_SEQ + k0 + tx * 4];
            const int mka[4] = {mk.x, mk.y, mk.z, mk.w};
#pragma unroll
            for (int i = 0; i < 4; ++i)
#pragma unroll
                for (int j = 0; j < 4; ++j)
                    s[i][j] = mka[j] ? (s[i][j] + bv[i][j]) : -FLT_MAX;

            // online softmax per row (16 tx lanes per row-group)
#pragma unroll
            for (int i = 0; i < 4; ++i) {
                float rm = fmaxf(fmaxf(s[i][0], s[i][1]), fmaxf(s[i][2], s[i][3]));
#pragma unroll
                for (int off = 1; off <= 8; off <<= 1)
                    rm = fmaxf(rm, __shfl_xor(rm, off, 64));
                float mo = m_r[b][i];
                float mn = fmaxf(mo, rm);
                float sc = __expf(mo - mn);          // mo=-inf -> 0
                float p0 = __expf(s[i][0] - mn);
                float p1 = __expf(s[i][1] - mn);
                float p2 = __expf(s[i][2] - mn);
                float p3 = __expf(s[i][3] - mn);
                float rs = (p0 + p1) + (p2 + p3);
#pragma unroll
                for (int off = 1; off <= 8; off <<= 1)
                    rs += __shfl_xor(rs, off, 64);
                m_r[b][i]  = mn;
                sc_r[b][i] = sc;
                l_r[b][i]  = l_r[b][i] * sc + rs;
                Ps[b][tx * 4 + 0][ty * 4 + i] = p0;
                Ps[b][tx * 4 + 1][ty * 4 + i] = p1;
                Ps[b][tx * 4 + 2][ty * 4 + i] = p2;
                Ps[b][tx * 4 + 3][ty * 4 + i] = p3;
            }
        }
        __syncthreads();   // Ps visible

        // PV accumulate
#pragma unroll
        for (int b = 0; b < 2; ++b) {
#pragma unroll
            for (int i = 0; i < 4; ++i)
#pragma unroll
                for (int j = 0; j < 4; ++j) O[b][i][j] *= sc_r[b][i];
#pragma unroll 8
            for (int kj = 0; kj < 64; ++kj) {
                float4 p4 = *(const float4*)&Ps[b][kj][ty * 4];
                float4 v4 = *(const float4*)&Vs[b][kj][tx * 4];
                float pa[4] = {p4.x, p4.y, p4.z, p4.w};
                float va[4] = {v4.x, v4.y, v4.z, v4.w};
#pragma unroll
                for (int i = 0; i < 4; ++i)
#pragma unroll
                    for (int j = 0; j < 4; ++j)
                        O[b][i][j] = fmaf(pa[i], va[j], O[b][i][j]);
            }
        }
    }

    // epilogue: normalize and store
#pragma unroll
    for (int b = 0; b < 2; ++b)
#pragma unroll
        for (int i = 0; i < 4; ++i) {
            float inv = 1.f / l_r[b][i];
            size_t row = ((size_t)(b * L_SEQ + q0 + ty * 4 + i)) * 1024 + h * 64 + tx * 4;
            *(float4*)&Aout[row] = make_float4(O[b][i][0] * inv, O[b][i][1] * inv,
                                               O[b][i][2] * inv, O[b][i][3] * inv);
        }
}

// ---------------------------------------------------------------------------
extern "C" void kernel_launch(void* const* d_in, const int* in_sizes, int n_in,
                              void* d_out, int out_size, void* d_ws, size_t ws_size,
                              hipStream_t stream)
{
    (void)in_sizes; (void)n_in; (void)out_size; (void)ws_size;
    const float* x    = (const float*)d_in[0];
    const int*   mask = (const int*)d_in[1];
    const float* bias = (const float*)d_in[2];
    const float* Wq   = (const float*)d_in[3];
    const float* Wk   = (const float*)d_in[4];
    const float* Wv   = (const float*)d_in[5];
    const float* Wo   = (const float*)d_in[6];
    float* out = (float*)d_out;

    const size_t MN = (size_t)2 * L_SEQ * 1024;  // 4 Mi elements
    float* Q = (float*)d_ws;
    float* K = Q + MN;
    float* V = K + MN;
    float* A = V + MN;   // attention output, pre-Wo   (total ws use: 64 MiB)

    dim3 g1(32, 8, 3);
    gemm_f32<<<g1, 256, 0, stream>>>(x, Wq, Wk, Wv, Q, K, V);

    dim3 g2(32, 16, 1);
    attn_f32<<<g2, 256, 0, stream>>>(Q, K, V, bias, mask, A);

    dim3 g3(32, 8, 1);
    gemm_f32<<<g3, 256, 0, stream>>>(A, Wo, Wo, Wo, out, out, out);
}

// Round 4
// 681.030 us; speedup vs baseline: 2.0938x; 2.0938x over previous
//
#include <hip/hip_runtime.h>
#include <float.h>
#include <math.h>

// B=2, L=2048, DIM=DIM_ATTN=1024, 16 heads x 64
typedef short s16x8 __attribute__((ext_vector_type(8)));
typedef float f32x4 __attribute__((ext_vector_type(4)));
typedef unsigned short u16t;
typedef u16t u16x4v __attribute__((ext_vector_type(4)));

__device__ __forceinline__ u16t f2bf(float f){
  unsigned u = __builtin_bit_cast(unsigned, f);
  return (u16t)((u + 0x7FFFu + ((u >> 16) & 1u)) >> 16);   // RNE; inputs always finite/small
}
__device__ __forceinline__ float bf2f(u16t b){
  unsigned u = ((unsigned)b) << 16;
  return __builtin_bit_cast(float, u);
}
__device__ __forceinline__ f32x4 mfma16(s16x8 a, s16x8 b, f32x4 c){
  return __builtin_amdgcn_mfma_f32_16x16x32_bf16(a, b, c, 0, 0, 0);
}

// ---------------- prep: split fp32 -> bf16 hi/lo -----------------------------
__global__ __launch_bounds__(256) void prep_split(const float* __restrict__ X,
    u16t* __restrict__ H, u16t* __restrict__ L, int n8){
  int i = blockIdx.x * 256 + threadIdx.x;
  if (i >= n8) return;
  const float* p = X + (size_t)i * 8;
  float4 a = *(const float4*)p;
  float4 b = *(const float4*)(p + 4);
  float v[8] = {a.x, a.y, a.z, a.w, b.x, b.y, b.z, b.w};
  s16x8 hv, lv;
#pragma unroll
  for (int r = 0; r < 8; ++r){
    u16t hh = f2bf(v[r]);
    hv[r] = (short)hh;
    lv[r] = (short)f2bf(v[r] - bf2f(hh));
  }
  *(s16x8*)(H + (size_t)i * 8) = hv;
  *(s16x8*)(L + (size_t)i * 8) = lv;
}

// ---------------- prep: transpose weights [K][N]->[N][K] + split -------------
__global__ __launch_bounds__(256) void prep_wt(
    const float* __restrict__ Wq, const float* __restrict__ Wk,
    const float* __restrict__ Wv, const float* __restrict__ Wo,
    u16t* __restrict__ Qh, u16t* __restrict__ Ql,
    u16t* __restrict__ Kh, u16t* __restrict__ Kl,
    u16t* __restrict__ Vh,
    u16t* __restrict__ Oh, u16t* __restrict__ Ol){
  __shared__ float T[64][65];
  int z = blockIdx.z;
  const float* W = (z==0)?Wq:(z==1)?Wk:(z==2)?Wv:Wo;
  u16t* OH = (z==0)?Qh:(z==1)?Kh:(z==2)?Vh:Oh;
  u16t* OL = (z==0)?Ql:(z==1)?Kl:(z==2)?(u16t*)0:Ol;
  int k0 = blockIdx.x*64, n0 = blockIdx.y*64;
  int r = threadIdx.x >> 2, c = (threadIdx.x & 3) * 16;
#pragma unroll
  for (int i = 0; i < 4; ++i){
    float4 v = *(const float4*)&W[(size_t)(k0 + r)*1024 + n0 + c + i*4];
    T[r][c + i*4 + 0] = v.x; T[r][c + i*4 + 1] = v.y;
    T[r][c + i*4 + 2] = v.z; T[r][c + i*4 + 3] = v.w;
  }
  __syncthreads();
  // out[n][k] = W[k][n]; this thread: n = n0+r, k = k0+c .. +15
  s16x8 hv0, hv1, lv0, lv1;
#pragma unroll
  for (int i = 0; i < 16; ++i){
    float v = T[c + i][r];
    u16t hh = f2bf(v);
    u16t ll = f2bf(v - bf2f(hh));
    if (i < 8){ hv0[i] = (short)hh; lv0[i] = (short)ll; }
    else      { hv1[i-8] = (short)hh; lv1[i-8] = (short)ll; }
  }
  size_t o = (size_t)(n0 + r)*1024 + k0 + c;
  *(s16x8*)(OH + o)     = hv0;
  *(s16x8*)(OH + o + 8) = hv1;
  if (OL){ *(s16x8*)(OL + o) = lv0; *(s16x8*)(OL + o + 8) = lv1; }
}

// ---------------- MFMA GEMM: C[4096,1024] = A[4096,1024] @ B^T-layout --------
// A row-major bf16 (hi/lo), B given TRANSPOSED [N][K] bf16 (hi/lo).
// NSPLIT=3: acc += AhBh + AhBl + AlBh (fp32-quality). NSPLIT=1: plain bf16.
// MODE 0: bf16 hi/lo row-major out (Q/K). MODE 1: bf16 V^T[n][token] packed.
// MODE 2: fp32 row-major out.
template<int NSPLIT, int MODE>
__global__ __launch_bounds__(256) void gemm_k(
    const u16t* __restrict__ Agh, const u16t* __restrict__ Agl,
    const u16t* __restrict__ Bgh0, const u16t* __restrict__ Bgl0,
    const u16t* __restrict__ Bgh1, const u16t* __restrict__ Bgl1,
    u16t* __restrict__ Oh0, u16t* __restrict__ Ol0,
    u16t* __restrict__ Oh1, u16t* __restrict__ Ol1,
    float* __restrict__ Of)
{
  constexpr int NPLANES = (NSPLIT==3) ? 4 : 2;
  __shared__ u16t SM[NPLANES * 4096];          // planes of [128 rows][32 k] bf16
  u16t* AH = SM;
  u16t* AL = SM + 4096;                        // valid only when NSPLIT==3
  u16t* BH = SM + ((NSPLIT==3) ? 8192 : 4096);
  u16t* BL = SM + 12288;                       // valid only when NSPLIT==3

  const u16t* Bgh = blockIdx.z ? Bgh1 : Bgh0;
  const u16t* Bgl = blockIdx.z ? Bgl1 : Bgl0;
  u16t* Oh = blockIdx.z ? Oh1 : Oh0;
  u16t* Ol = blockIdx.z ? Ol1 : Ol0;

  const int t = threadIdx.x;
  const int lane = t & 63;
  const int wid = t >> 6;
  const int wm = wid >> 1, wn = wid & 1;       // 2x2 waves, 64x64 each
  const int bm = blockIdx.x * 128, bn = blockIdx.y * 128;
  const int li = lane & 15, lg = lane >> 4;

  f32x4 acc[4][4];
#pragma unroll
  for (int i = 0; i < 4; ++i)
#pragma unroll
    for (int j = 0; j < 4; ++j) acc[i][j] = f32x4{0.f, 0.f, 0.f, 0.f};

  for (int k0 = 0; k0 < 1024; k0 += 32){
    __syncthreads();
#pragma unroll
    for (int i = 0; i < 2; ++i){
      int cch = i*256 + t;                     // 512 chunks = 128 rows x 4 slots
      int row = cch >> 2, sl = cch & 3;
      int sw = (sl ^ ((row >> 1) & 3)) * 8;    // XOR swizzle (16B slots)
      *(s16x8*)&AH[row*32 + sw] = *(const s16x8*)&Agh[(size_t)(bm+row)*1024 + k0 + sl*8];
      if constexpr (NSPLIT == 3)
        *(s16x8*)&AL[row*32 + sw] = *(const s16x8*)&Agl[(size_t)(bm+row)*1024 + k0 + sl*8];
      *(s16x8*)&BH[row*32 + sw] = *(const s16x8*)&Bgh[(size_t)(bn+row)*1024 + k0 + sl*8];
      if constexpr (NSPLIT == 3)
        *(s16x8*)&BL[row*32 + sw] = *(const s16x8*)&Bgl[(size_t)(bn+row)*1024 + k0 + sl*8];
    }
    __syncthreads();

    s16x8 ah[4], alv[4], bh[4], blv[4];
#pragma unroll
    for (int i = 0; i < 4; ++i){
      int rowA = wm*64 + i*16 + li;
      int swA = (lg ^ ((rowA >> 1) & 3)) * 8;
      ah[i] = *(const s16x8*)&AH[rowA*32 + swA];
      if constexpr (NSPLIT == 3) alv[i] = *(const s16x8*)&AL[rowA*32 + swA];
      int rowB = wn*64 + i*16 + li;
      int swB = (lg ^ ((rowB >> 1) & 3)) * 8;
      bh[i] = *(const s16x8*)&BH[rowB*32 + swB];
      if constexpr (NSPLIT == 3) blv[i] = *(const s16x8*)&BL[rowB*32 + swB];
    }
#pragma unroll
    for (int i = 0; i < 4; ++i)
#pragma unroll
      for (int j = 0; j < 4; ++j){
        acc[i][j] = mfma16(ah[i], bh[j], acc[i][j]);
        if constexpr (NSPLIT == 3){
          acc[i][j] = mfma16(ah[i], blv[j], acc[i][j]);
          acc[i][j] = mfma16(alv[i], bh[j], acc[i][j]);
        }
      }
  }

  // epilogue: C/D frag = D[(lg*4+r)][li] per 16x16 tile (m89-verified layout)
#pragma unroll
  for (int i = 0; i < 4; ++i)
#pragma unroll
    for (int j = 0; j < 4; ++j){
      if constexpr (MODE == 1){
        int n = bn + wn*64 + j*16 + li;
        int tok0 = bm + wm*64 + i*16 + lg*4;
        u16x4v pk;
#pragma unroll
        for (int r = 0; r < 4; ++r) pk[r] = f2bf(acc[i][j][r]);
        *(u16x4v*)&Oh[(size_t)n*4096 + tok0] = pk;   // V^T[n][token], 4 tokens packed
      } else {
#pragma unroll
        for (int r = 0; r < 4; ++r){
          int tok = bm + wm*64 + i*16 + lg*4 + r;
          int col = bn + wn*64 + j*16 + li;
          float v = acc[i][j][r];
          if constexpr (MODE == 0){
            u16t hh = f2bf(v);
            Oh[(size_t)tok*1024 + col] = hh;
            Ol[(size_t)tok*1024 + col] = f2bf(v - bf2f(hh));
          } else {
            Of[(size_t)tok*1024 + col] = v;
          }
        }
      }
    }
}

// ---------------- MFMA flash attention ---------------------------------------
// Block = (64-q-tile, head); 4 waves, each owns 16 q-rows; both batches.
// Swapped QK^T: S^T = mfma(K, Q) so lane (li) owns one q-row for softmax.
// Split-3 QK^T; plain-bf16 PV with V^T staged from the V-GEMM's transposed output.
__global__ __launch_bounds__(256) void attn_mfma(
    const u16t* __restrict__ Qh, const u16t* __restrict__ Ql,
    const u16t* __restrict__ Kh, const u16t* __restrict__ Kl,
    const u16t* __restrict__ Vt, const float* __restrict__ bias,
    const int* __restrict__ mask,
    u16t* __restrict__ Ah, u16t* __restrict__ Al)
{
  __shared__ u16t SM[6 * 4096];        // {b0,b1} x {Kh,Kl,V^T} tiles [64][64] bf16
  __shared__ u16t PL[4][16 * 72];      // per-wave P [16 qi][64 kj] bf16, padded

  const int t = threadIdx.x, lane = t & 63, wid = t >> 6;
  const int h = blockIdx.y;
  const int q0 = blockIdx.x * 64;
  const int lg = lane >> 4, li = lane & 15;
  const int qrow = q0 + wid*16 + li;          // this lane's softmax row

  s16x8 qf[2][2][2];                          // [batch][k-chunk][hi/lo]
#pragma unroll
  for (int b = 0; b < 2; ++b)
#pragma unroll
    for (int c = 0; c < 2; ++c){
      size_t o = (size_t)(b*2048 + qrow)*1024 + h*64 + c*32 + lg*8;
      qf[b][c][0] = *(const s16x8*)&Qh[o];
      qf[b][c][1] = *(const s16x8*)&Ql[o];
    }

  f32x4 Oacc[2][4];
#pragma unroll
  for (int b = 0; b < 2; ++b)
#pragma unroll
    for (int d = 0; d < 4; ++d) Oacc[b][d] = f32x4{0.f,0.f,0.f,0.f};
  float m_s[2] = {-__builtin_inff(), -__builtin_inff()};
  float l_s[2] = {0.f, 0.f};

  for (int k0 = 0; k0 < 2048; k0 += 64){
    __syncthreads();
#pragma unroll
    for (int p = 0; p < 6; ++p){
      int b = (p >= 3) ? 1 : 0, kind = p - b*3;
#pragma unroll
      for (int i = 0; i < 2; ++i){
        int cch = i*256 + t;                  // 512 chunks = 64 rows x 8 slots
        int row = cch >> 3, sl = cch & 7;
        const u16t* src;
        if (kind == 0)      src = &Kh[(size_t)(b*2048 + k0 + row)*1024 + h*64 + sl*8];
        else if (kind == 1) src = &Kl[(size_t)(b*2048 + k0 + row)*1024 + h*64 + sl*8];
        else                src = &Vt[(size_t)(h*64 + row)*4096 + b*2048 + k0 + sl*8];
        *(s16x8*)&SM[p*4096 + row*64 + ((sl ^ (row & 7)) * 8)] = *(const s16x8*)src;
      }
    }
    __syncthreads();

#pragma unroll
    for (int b = 0; b < 2; ++b){
      const u16t* KHL = SM + (b*3+0)*4096;
      const u16t* KLL = SM + (b*3+1)*4096;
      const u16t* VTL = SM + (b*3+2)*4096;

      // S^T tiles: D[kj-local][qi=li]
      f32x4 sa[4];
#pragma unroll
      for (int tt = 0; tt < 4; ++tt) sa[tt] = f32x4{0.f,0.f,0.f,0.f};
#pragma unroll
      for (int tt = 0; tt < 4; ++tt)
#pragma unroll
        for (int c = 0; c < 2; ++c){
          int row = tt*16 + li;
          int off = row*64 + (((c*4 + lg) ^ (row & 7)) * 8);
          s16x8 kh = *(const s16x8*)&KHL[off];
          s16x8 kl = *(const s16x8*)&KLL[off];
          sa[tt] = mfma16(kh, qf[b][c][0], sa[tt]);
          sa[tt] = mfma16(kh, qf[b][c][1], sa[tt]);
          sa[tt] = mfma16(kl, qf[b][c][0], sa[tt]);
        }

      // bias + mask + online softmax (lane owns row qrow; kj = k0+tt*16+lg*4+r)
      float pv[4][4];
      float rm = -FLT_MAX;
#pragma unroll
      for (int tt = 0; tt < 4; ++tt){
        float4 bb = *(const float4*)&bias[(size_t)(h*2048 + qrow)*2048 + k0 + tt*16 + lg*4];
        int4 mk = *(const int4*)&mask[b*2048 + k0 + tt*16 + lg*4];
        float ba[4] = {bb.x, bb.y, bb.z, bb.w};
        int ma[4] = {mk.x, mk.y, mk.z, mk.w};
#pragma unroll
        for (int r = 0; r < 4; ++r){
          float s = (ma[r] > 0) ? sa[tt][r] + ba[r] : -FLT_MAX;
          pv[tt][r] = s;
          rm = fmaxf(rm, s);
        }
      }
      rm = fmaxf(rm, __shfl_xor(rm, 16, 64));
      rm = fmaxf(rm, __shfl_xor(rm, 32, 64));
      float mo = m_s[b];
      float mn = fmaxf(mo, rm);
      float sc = __expf(mo - mn);             // -inf - finite -> 0
      float rs = 0.f;
#pragma unroll
      for (int tt = 0; tt < 4; ++tt)
#pragma unroll
        for (int r = 0; r < 4; ++r){
          float p = __expf(pv[tt][r] - mn);
          pv[tt][r] = p;
          rs += p;
        }
      rs += __shfl_xor(rs, 16, 64);
      rs += __shfl_xor(rs, 32, 64);
      m_s[b] = mn;
      l_s[b] = l_s[b]*sc + rs;

      // P -> per-wave LDS [qi][kj] (bf16)
#pragma unroll
      for (int tt = 0; tt < 4; ++tt){
        u16x4v pk;
#pragma unroll
        for (int r = 0; r < 4; ++r) pk[r] = f2bf(pv[tt][r]);
        *(u16x4v*)&PL[wid][li*72 + tt*16 + lg*4] = pk;
      }

      // rescale O (O-frag rows are qi' = lg*4+r; fetch sc from lane qi')
      float scb[4];
#pragma unroll
      for (int r = 0; r < 4; ++r) scb[r] = __shfl(sc, lg*4 + r, 64);
#pragma unroll
      for (int d = 0; d < 4; ++d)
#pragma unroll
        for (int r = 0; r < 4; ++r) Oacc[b][d][r] *= scb[r];

      // PV: A = P (row qi=li, kj consec), B = V^T tile (col dk=li, kj consec)
      s16x8 pf[2];
#pragma unroll
      for (int c = 0; c < 2; ++c)
        pf[c] = *(const s16x8*)&PL[wid][li*72 + c*32 + lg*8];
#pragma unroll
      for (int d = 0; d < 4; ++d)
#pragma unroll
        for (int c = 0; c < 2; ++c){
          int row = d*16 + li;
          s16x8 vf = *(const s16x8*)&VTL[row*64 + (((c*4 + lg) ^ (row & 7)) * 8)];
          Oacc[b][d] = mfma16(pf[c], vf, Oacc[b][d]);
        }
    }
  }

  // epilogue: normalize, split to bf16 hi/lo, row-major [token][1024]
#pragma unroll
  for (int b = 0; b < 2; ++b){
    float inv[4];
#pragma unroll
    for (int r = 0; r < 4; ++r){
      float lr = __shfl(l_s[b], lg*4 + r, 64);
      inv[r] = 1.f / lr;
    }
#pragma unroll
    for (int d = 0; d < 4; ++d)
#pragma unroll
      for (int r = 0; r < 4; ++r){
        size_t tok = (size_t)(b*2048 + q0 + wid*16 + lg*4 + r);
        int col = h*64 + d*16 + li;
        float v = Oacc[b][d][r] * inv[r];
        u16t hh = f2bf(v);
        Ah[tok*1024 + col] = hh;
        Al[tok*1024 + col] = f2bf(v - bf2f(hh));
      }
  }
}

// -----------------------------------------------------------------------------
extern "C" void kernel_launch(void* const* d_in, const int* in_sizes, int n_in,
                              void* d_out, int out_size, void* d_ws, size_t ws_size,
                              hipStream_t stream)
{
  (void)in_sizes; (void)n_in; (void)out_size; (void)ws_size;
  const float* x    = (const float*)d_in[0];
  const int*   mask = (const int*)d_in[1];
  const float* bias = (const float*)d_in[2];
  const float* Wq   = (const float*)d_in[3];
  const float* Wk   = (const float*)d_in[4];
  const float* Wv   = (const float*)d_in[5];
  const float* Wo   = (const float*)d_in[6];
  float* out = (float*)d_out;

  uint8_t* wsb = (uint8_t*)d_ws;
  const size_t MB = (size_t)1 << 20;
  u16t* Xh   = (u16t*)(wsb +  0*MB);   // 8 MB  (reused as attn-out hi)
  u16t* Xl   = (u16t*)(wsb +  8*MB);   // 8 MB  (reused as attn-out lo)
  u16t* Wqth = (u16t*)(wsb + 16*MB);   // 2 MB each; [16,24) reused as V^T later
  u16t* Wqtl = (u16t*)(wsb + 18*MB);
  u16t* Wkth = (u16t*)(wsb + 20*MB);
  u16t* Wktl = (u16t*)(wsb + 22*MB);
  u16t* Wvth = (u16t*)(wsb + 24*MB);
  u16t* Woth = (u16t*)(wsb + 26*MB);
  u16t* Wotl = (u16t*)(wsb + 28*MB);
  u16t* Qh_  = (u16t*)(wsb + 30*MB);   // 8 MB
  u16t* Ql_  = (u16t*)(wsb + 38*MB);
  u16t* Kh_  = (u16t*)(wsb + 46*MB);
  u16t* Kl_  = (u16t*)(wsb + 54*MB);   // total 62 MB
  u16t* Vt_  = (u16t*)(wsb + 16*MB);   // V^T[1024][4096], overlays dead Wq/Wk planes
  u16t* Aath = Xh;                     // attn out hi, overlays dead Xh
  u16t* Aatl = Xl;

  prep_split<<<dim3(2048), 256, 0, stream>>>(x, Xh, Xl, 4096*1024/8);
  prep_wt<<<dim3(16,16,4), 256, 0, stream>>>(Wq, Wk, Wv, Wo,
      Wqth, Wqtl, Wkth, Wktl, Wvth, Woth, Wotl);

  // Q and K projections (split-3, bf16 hi/lo out)
  gemm_k<3,0><<<dim3(32,8,2), 256, 0, stream>>>(Xh, Xl, Wqth, Wqtl, Wkth, Wktl,
      Qh_, Ql_, Kh_, Kl_, nullptr);
  // V projection (plain bf16, transposed output V^T)
  gemm_k<1,1><<<dim3(32,8,1), 256, 0, stream>>>(Xh, nullptr, Wvth, nullptr,
      nullptr, nullptr, Vt_, nullptr, nullptr, nullptr, nullptr);

  attn_mfma<<<dim3(32,16), 256, 0, stream>>>(Qh_, Ql_, Kh_, Kl_, Vt_, bias, mask,
      Aath, Aatl);

  // output projection (split-3, fp32 out)
  gemm_k<3,2><<<dim3(32,8,1), 256, 0, stream>>>(Aath, Aatl, Woth, Wotl,
      nullptr, nullptr, nullptr, nullptr, nullptr, nullptr, out);
}